// Round 10
// baseline (451.192 us; speedup 1.0000x reference)
//
#include <hip/hip_runtime.h>

#define H    64
#define F    256
#define NSEG 256
#define SCB  2048   // scan elements per block
#define MB   64     // qkv node rows per tile
#define KC   64     // qkv K chunk
#define NSPAN_MAX 8192
#define RCH  4096   // reorder edges per work-queue chunk

typedef float          f32x4v __attribute__((ext_vector_type(4)));
typedef short          bf16x8 __attribute__((ext_vector_type(8)));
typedef unsigned short u16x4  __attribute__((ext_vector_type(4)));

__device__ __forceinline__ int xcc_id() {
    int x;
    asm volatile("s_getreg_b32 %0, hwreg(HW_REG_XCC_ID)" : "=s"(x));
    return x & 7;
}

// ---------------------------------------------------------------------------
// In-degree histogram: LDS-privatized, zero global atomics (R9-verified).
// Grid = 8 spans x 8 chunks; LDS histogram per block; non-atomic flush to
// counts8[chunk]; scanA sums the 8 copies.
// ---------------------------------------------------------------------------
__global__ __launch_bounds__(1024) void hist8_kernel(
    const int* __restrict__ ei, int* __restrict__ counts8,
    int N, int E, int nspan)
{
    __shared__ int lh[NSPAN_MAX];
    const int p  = blockIdx.x & 7;           // span class
    const int c  = blockIdx.x >> 3;          // edge chunk 0..7
    const int lo = p * nspan;
    const int span = min(N - lo, nspan);
    const int t = threadIdx.x;

    for (int i = t; i < span; i += 1024) lh[i] = 0;
    __syncthreads();

    const int epc = (E + 7) >> 3;            // edges per chunk
    const int e0 = c * epc;
    const int e1 = min(E, e0 + epc);

    if (((E + e0) & 3) == 0) {               // 16B-aligned vector path
        const int nv = (e1 - e0) >> 2;
        for (int i = t; i < nv; i += 1024) {
            const int4 d4 = *(const int4*)(ei + E + e0 + i * 4);
            int d;
            d = min(max(d4.x, 0), N - 1) - lo; if ((unsigned)d < (unsigned)span) atomicAdd(&lh[d], 1);
            d = min(max(d4.y, 0), N - 1) - lo; if ((unsigned)d < (unsigned)span) atomicAdd(&lh[d], 1);
            d = min(max(d4.z, 0), N - 1) - lo; if ((unsigned)d < (unsigned)span) atomicAdd(&lh[d], 1);
            d = min(max(d4.w, 0), N - 1) - lo; if ((unsigned)d < (unsigned)span) atomicAdd(&lh[d], 1);
        }
        for (int e = e0 + nv * 4 + t; e < e1; e += 1024) {
            const int d = min(max(ei[E + e], 0), N - 1) - lo;
            if ((unsigned)d < (unsigned)span) atomicAdd(&lh[d], 1);
        }
    } else {
        for (int e = e0 + t; e < e1; e += 1024) {
            const int d = min(max(ei[E + e], 0), N - 1) - lo;
            if ((unsigned)d < (unsigned)span) atomicAdd(&lh[d], 1);
        }
    }
    __syncthreads();

    for (int i = t; i < span; i += 1024) counts8[(size_t)c * N + lo + i] = lh[i];
}

// ---------------------------------------------------------------------------
// QKV GEMM, persistent-W + XOR-swizzled LDS.  R9 post-mortem: XPAD=72 rows
// (36-dword stride) put the 16-lane fragment reads on a 4r%32 bank pattern
// -> SQ_LDS_BANK_CONFLICT 2.4M cyc/dispatch (~4us/CU).  Now: no pad, 128B
// rows, 16B-block index XORed with row&7 -> ds_read_b128 spreads over 8
// bank-quads 2-way (free).  LDS 36.9->32 KB.
//   acc += xh*wh + xh*wl + xl*wh    (xl*wl ~ 2^-17 dropped)
// ---------------------------------------------------------------------------
#define CVT_WRITE(buf, rr, cc, val) do {                                      \
    const float ff_[4] = {(val).x, (val).y, (val).z, (val).w};                \
    u16x4 h_, l_;                                                             \
    _Pragma("unroll")                                                         \
    for (int u_ = 0; u_ < 4; ++u_) {                                          \
        unsigned ub_ = __float_as_uint(ff_[u_]);                              \
        h_[u_] = (unsigned short)(ub_ >> 16);                                 \
        float rf_ = ff_[u_] - __uint_as_float(ub_ & 0xFFFF0000u);             \
        l_[u_] = (unsigned short)(__float_as_uint(rf_) >> 16);                \
    }                                                                         \
    const int so_ = (rr) * 64 + (((((cc) >> 1) ^ ((rr) & 7))) << 3)           \
                  + ((cc) & 1) * 4;                                           \
    *(u16x4*)&xs_hi[buf][so_] = h_;                                           \
    *(u16x4*)&xs_lo[buf][so_] = l_;                                           \
} while (0)

__global__ __launch_bounds__(768, 3) void qkv_mfma(
    const float* __restrict__ x,
    const float* __restrict__ Wq, const float* __restrict__ Wk,
    const float* __restrict__ Wv,
    const float* __restrict__ bq, const float* __restrict__ bk,
    const float* __restrict__ bv,
    float* __restrict__ q, float* __restrict__ k, float* __restrict__ v,
    int N, int ntiles)
{
    __shared__ unsigned short xs_hi[2][MB * 64];   // 2 x 8 KB, swizzled
    __shared__ unsigned short xs_lo[2][MB * 64];   // 2 x 8 KB, swizzled

    const int t    = threadIdx.x;
    const int lane = t & 63;
    const int w    = t >> 6;        // 0..11
    const int mat  = w >> 2;        // 0..2  (Q,K,V)
    const int ct   = w & 3;         // 16-col tile
    const int l15  = lane & 15;
    const int quad = lane >> 4;

    const float* Wm   = (mat == 0) ? Wq : (mat == 1) ? Wk : Wv;
    const float* bias = (mat == 0) ? bq : (mat == 1) ? bk : bv;
    float*       dst  = (mat == 0) ? q  : (mat == 1) ? k  : v;
    const int col = ct * 16 + l15;
    const float bb = bias[col];

    // ---- W preload: full-K B fragments in registers, split hi/lo in-reg ---
    bf16x8 Bh[8], Bl[8];
    #pragma unroll
    for (int u = 0; u < 8; ++u) {
        #pragma unroll
        for (int j = 0; j < 8; ++j) {
            const float f = Wm[(size_t)(u * 32 + quad * 8 + j) * H + col];
            const unsigned ub = __float_as_uint(f);
            Bh[u][j] = (short)(ub >> 16);
            const float rf = f - __uint_as_float(ub & 0xFFFF0000u);
            Bl[u][j] = (short)(__float_as_uint(rf) >> 16);
        }
    }

    // staging slots: 1024 float4 per chunk; thread t does slot t (always)
    // and slot t+768 (t<256).  (t+768)&15 == t&15 since 768 % 16 == 0.
    const int r0 = t >> 4;
    const int c0 = t & 15;
    const int r1 = (t + 768) >> 4;

    // swizzled read offsets (row & 7 == l15 & 7)
    const int swz = (l15 & 7);

    #pragma unroll 1
    for (int tile = blockIdx.x; tile < ntiles; tile += gridDim.x) {
        const int block0 = tile * MB;

        f32x4v acc[4];
        #pragma unroll
        for (int i = 0; i < 4; ++i) acc[i] = (f32x4v)0.f;

        // ---- prologue: chunk 0 into buffer 0 ----
        float4 pv0, pv1;
        pv0 = *(const float4*)(x + (size_t)min(block0 + r0, N - 1) * F + c0 * 4);
        if (t < 256)
            pv1 = *(const float4*)(x + (size_t)min(block0 + r1, N - 1) * F + c0 * 4);
        CVT_WRITE(0, r0, c0, pv0);
        if (t < 256) CVT_WRITE(0, r1, c0, pv1);

        #pragma unroll
        for (int c = 0; c < 4; ++c) {
            __syncthreads();          // buf[c&1] writes visible to all waves

            // issue next chunk's loads EARLY (consumed after the MFMAs)
            if (c < 3) {
                const int kb = (c + 1) * KC;
                pv0 = *(const float4*)(x + (size_t)min(block0 + r0, N - 1) * F + kb + c0 * 4);
                if (t < 256)
                    pv1 = *(const float4*)(x + (size_t)min(block0 + r1, N - 1) * F + kb + c0 * 4);
            }

            // MFMA burst on buf[c&1]; B frags from registers (u = c*2+sk)
            #pragma unroll
            for (int sk = 0; sk < 2; ++sk) {
                const int u = c * 2 + sk;
                #pragma unroll
                for (int mt = 0; mt < 4; ++mt) {
                    const int row = mt * 16 + l15;
                    const int ao  = row * 64 + (((sk * 4 + quad) ^ swz) << 3);
                    const bf16x8 ah = *(const bf16x8*)&xs_hi[c & 1][ao];
                    const bf16x8 al = *(const bf16x8*)&xs_lo[c & 1][ao];
                    f32x4v a = acc[mt];
                    a = __builtin_amdgcn_mfma_f32_16x16x32_bf16(ah, Bh[u], a, 0, 0, 0);
                    a = __builtin_amdgcn_mfma_f32_16x16x32_bf16(ah, Bl[u], a, 0, 0, 0);
                    a = __builtin_amdgcn_mfma_f32_16x16x32_bf16(al, Bh[u], a, 0, 0, 0);
                    acc[mt] = a;
                }
            }

            // convert + write next chunk into the other buffer (WAR-safe:
            // buf[nxt] last read in chunk c-1, all waves past top-of-c barrier)
            if (c < 3) {
                const int nb = (c & 1) ^ 1;
                CVT_WRITE(nb, r0, c0, pv0);
                if (t < 256) CVT_WRITE(nb, r1, c0, pv1);
            }
        }

        // epilogue: C layout col = lane&15, row = quad*4 + reg (m89-verified)
        #pragma unroll
        for (int mt = 0; mt < 4; ++mt) {
            #pragma unroll
            for (int r = 0; r < 4; ++r) {
                const int node = block0 + mt * 16 + quad * 4 + r;
                if (node < N)
                    dst[(size_t)node * H + col] = acc[mt][r] + bb;
            }
        }
    }
}

// ---------------------------------------------------------------------------
// Scan phase A/B/C: exclusive scan of padded (x4) per-node counts.
// scanA sums the 8 per-chunk histogram copies and emits merged counts.
// ---------------------------------------------------------------------------
__global__ __launch_bounds__(256) void scanA(
    const int* __restrict__ counts8, int* __restrict__ counts,
    int* __restrict__ offsets, int* __restrict__ bsum, int n)
{
    __shared__ int ps[256];
    const int t = threadIdx.x;
    const int i0 = blockIdx.x * SCB + t * 8;
    int loc[8];
    int s = 0;
    #pragma unroll
    for (int u = 0; u < 8; ++u) {
        int i = i0 + u;
        int c = 0;
        if (i < n) {
            #pragma unroll
            for (int p = 0; p < 8; ++p) c += counts8[(size_t)p * n + i];
            counts[i] = c;
            c = (c + 3) & ~3;
        }
        loc[u] = s; s += c;
    }
    ps[t] = s;
    __syncthreads();
    for (int off = 1; off < 256; off <<= 1) {
        int a = (t >= off) ? ps[t - off] : 0;
        __syncthreads();
        ps[t] += a;
        __syncthreads();
    }
    const int base = ps[t] - s;
    #pragma unroll
    for (int u = 0; u < 8; ++u) {
        int i = i0 + u;
        if (i < n) offsets[i] = base + loc[u];
    }
    if (t == 255) bsum[blockIdx.x] = ps[255];
}

__global__ void scanB(int* __restrict__ bsum, int nb)
{
    // single-wave shuffle exclusive scan (nb <= 64)
    const int t = threadIdx.x;
    int v = (t < nb) ? bsum[t] : 0;
    int inc = v;
    #pragma unroll
    for (int off = 1; off < 64; off <<= 1) {
        int u = __shfl_up(inc, off, 64);
        if (t >= off) inc += u;
    }
    if (t < nb) bsum[t] = inc - v;   // exclusive
}

__global__ __launch_bounds__(256) void scanC(
    const int* __restrict__ bsum, int* __restrict__ offsets,
    int* __restrict__ cursor, int n)
{
    const int i0 = blockIdx.x * SCB + threadIdx.x * 8;
    const int add = bsum[blockIdx.x];
    #pragma unroll
    for (int u = 0; u < 8; ++u) {
        int i = i0 + u;
        if (i < n) { int o = offsets[i] + add; offsets[i] = o; cursor[i] = o; }
    }
}

// ---------------------------------------------------------------------------
// Reorder edges into dst-node order, TRUE-XCD partitioned.  R9 post-mortem:
// blockIdx&7 is not the real XCD mapping (WRITE_SIZE stayed 32.5 MB = ~8.5
// HBM write-backs per epack line).  Now each block reads its actual XCD id
// (s_getreg HW_REG_XCC_ID, m09-verified) and serves the dst span matching
// it, claiming edge chunks from a per-class work queue -> every cursor and
// epack line is touched by exactly one XCD's L2.  After its own queue
// drains, a block steals from other classes (correct from any XCD, just
// slower) so coverage never depends on the dispatch mapping.
// ---------------------------------------------------------------------------
__global__ __launch_bounds__(256) void reorder_kernel(
    const int* __restrict__ ei, const int* __restrict__ batch,
    int* __restrict__ cursor, unsigned* __restrict__ epack,
    int* __restrict__ wq, int E, int N, int nspan, int nchunk)
{
    __shared__ int chunk_s;
    const int t   = threadIdx.x;
    const int xcd = xcc_id();

    for (int cc = 0; cc < 8; ++cc) {
        const int cls = (xcd + cc) & 7;
        const int lo  = cls * nspan;
        const int hi  = min(N, lo + nspan);
        for (;;) {
            __syncthreads();
            if (t == 0) chunk_s = atomicAdd(&wq[cls], 1);
            __syncthreads();
            const int ci = chunk_s;
            if (ci >= nchunk) break;
            const int base = ci * RCH;
            #pragma unroll
            for (int it = 0; it < 4; ++it) {
                const int e0 = base + it * 1024 + t * 4;
                if (e0 + 3 < E) {
                    const int4 d4 = *(const int4*)(ei + E + e0);
                    const int dd[4] = {d4.x, d4.y, d4.z, d4.w};
                    #pragma unroll
                    for (int u = 0; u < 4; ++u) {
                        const int dst = min(max(dd[u], 0), N - 1);
                        if (dst >= lo && dst < hi) {
                            const int src = min(max(ei[e0 + u], 0), N - 1);
                            const int seg = min(max(batch[src], 0), NSEG - 1);
                            const int pos = atomicAdd(&cursor[dst], 1);
                            epack[pos] = (unsigned)src | ((unsigned)seg << 16);
                        }
                    }
                } else {
                    for (int u = 0; u < 4; ++u) {
                        const int e = e0 + u;
                        if (e < E) {
                            const int dst = min(max(ei[E + e], 0), N - 1);
                            if (dst >= lo && dst < hi) {
                                const int src = min(max(ei[e], 0), N - 1);
                                const int seg = min(max(batch[src], 0), NSEG - 1);
                                const int pos = atomicAdd(&cursor[dst], 1);
                                epack[pos] = (unsigned)src | ((unsigned)seg << 16);
                            }
                        }
                    }
                }
            }
        }
    }
}

// ---------------------------------------------------------------------------
// Score: persistent grid, one wave per dst node; q[dst] in registers across
// its edges; 4 edges in flight (16-lane groups, float4 k gathers, 4-step
// shuffle reduce).  Per-block LDS denom histogram flushed once into the
// TRUE-XCD-local denom copy (xcc_id, not blockIdx&7).
// ---------------------------------------------------------------------------
__global__ __launch_bounds__(256) void score_kernel(
    const float* __restrict__ q, const float* __restrict__ k,
    const unsigned* __restrict__ epack,
    const int* __restrict__ offsets, const int* __restrict__ counts,
    float* __restrict__ exps, float* __restrict__ denom8, int N)
{
    __shared__ float sden[NSEG];
    const int t = threadIdx.x;
    sden[t] = 0.f;
    __syncthreads();

    const int lane16 = t & 15;
    const int grp    = (t >> 4) & 3;
    const int wave   = t >> 6;
    const int nwaves = gridDim.x * 4;

    const float4* q4 = (const float4*)q;
    const float4* k4 = (const float4*)k;

    for (int n = blockIdx.x * 4 + wave; n < N; n += nwaves) {
        const int off = offsets[n];
        const int cnt = counts[n];
        if (cnt == 0) continue;
        const float4 qv = q4[(size_t)n * 16 + lane16];
        for (int i = grp; i < cnt; i += 4) {
            const int pos = off + i;
            const unsigned p = epack[pos];
            const int src = p & 0xFFFF;
            const float4 kv = k4[(size_t)src * 16 + lane16];
            float d = kv.x * qv.x + kv.y * qv.y + kv.z * qv.z + kv.w * qv.w;
            d += __shfl_xor(d, 1, 64);
            d += __shfl_xor(d, 2, 64);
            d += __shfl_xor(d, 4, 64);
            d += __shfl_xor(d, 8, 64);
            if (lane16 == 0) {
                float ex = __expf(d * 0.125f);
                exps[pos] = ex;
                atomicAdd(&sden[(p >> 16) & 255], ex);
            }
        }
    }
    __syncthreads();
    float ds = sden[t];
    if (ds != 0.f) atomicAdd(&denom8[xcc_id() * NSEG + t], ds);
}

// ---------------------------------------------------------------------------
// Accumulate: one wave per dst node, lane = feature, register accumulator,
// zero atomics.  LDS reciprocal table built by summing the 8 denom copies.
// ---------------------------------------------------------------------------
__global__ __launch_bounds__(256) void accum_kernel(
    const float* __restrict__ v, const float* __restrict__ exps,
    const unsigned* __restrict__ epack,
    const int* __restrict__ offsets, const int* __restrict__ counts,
    const float* __restrict__ denom8, float* __restrict__ out, int N)
{
    __shared__ float rden[NSEG];
    const int t = threadIdx.x;
    {
        float dsum = 0.f;
        #pragma unroll
        for (int p = 0; p < 8; ++p) dsum += denom8[p * NSEG + t];
        rden[t] = 1.0f / (dsum + 1e-6f);
    }
    __syncthreads();

    const int lane = t & 63;
    const int wave = t >> 6;
    const int n = blockIdx.x * 4 + wave;
    if (n >= N) return;

    const int off = offsets[n];
    const int cnt = counts[n];

    float acc = 0.f;
    int i = 0;
    for (; i + 8 <= cnt; i += 8) {
        const uint4  pa = *(const uint4*)(epack + off + i);
        const uint4  pb = *(const uint4*)(epack + off + i + 4);
        const float4 ea = *(const float4*)(exps + off + i);
        const float4 eb = *(const float4*)(exps + off + i + 4);
        const float v0 = v[(size_t)(pa.x & 0xFFFF) * H + lane];
        const float v1 = v[(size_t)(pa.y & 0xFFFF) * H + lane];
        const float v2 = v[(size_t)(pa.z & 0xFFFF) * H + lane];
        const float v3 = v[(size_t)(pa.w & 0xFFFF) * H + lane];
        const float v4_ = v[(size_t)(pb.x & 0xFFFF) * H + lane];
        const float v5 = v[(size_t)(pb.y & 0xFFFF) * H + lane];
        const float v6 = v[(size_t)(pb.z & 0xFFFF) * H + lane];
        const float v7 = v[(size_t)(pb.w & 0xFFFF) * H + lane];
        acc = fmaf(v0, ea.x * rden[(pa.x >> 16) & 255], acc);
        acc = fmaf(v1, ea.y * rden[(pa.y >> 16) & 255], acc);
        acc = fmaf(v2, ea.z * rden[(pa.z >> 16) & 255], acc);
        acc = fmaf(v3, ea.w * rden[(pa.w >> 16) & 255], acc);
        acc = fmaf(v4_, eb.x * rden[(pb.x >> 16) & 255], acc);
        acc = fmaf(v5, eb.y * rden[(pb.y >> 16) & 255], acc);
        acc = fmaf(v6, eb.z * rden[(pb.z >> 16) & 255], acc);
        acc = fmaf(v7, eb.w * rden[(pb.w >> 16) & 255], acc);
    }
    for (; i + 4 <= cnt; i += 4) {
        const uint4  pp = *(const uint4*)(epack + off + i);
        const float4 ee = *(const float4*)(exps + off + i);
        const float v0 = v[(size_t)(pp.x & 0xFFFF) * H + lane];
        const float v1 = v[(size_t)(pp.y & 0xFFFF) * H + lane];
        const float v2 = v[(size_t)(pp.z & 0xFFFF) * H + lane];
        const float v3 = v[(size_t)(pp.w & 0xFFFF) * H + lane];
        acc = fmaf(v0, ee.x * rden[(pp.x >> 16) & 255], acc);
        acc = fmaf(v1, ee.y * rden[(pp.y >> 16) & 255], acc);
        acc = fmaf(v2, ee.z * rden[(pp.z >> 16) & 255], acc);
        acc = fmaf(v3, ee.w * rden[(pp.w >> 16) & 255], acc);
    }
    for (; i < cnt; ++i) {
        const unsigned p = epack[off + i];
        acc = fmaf(v[(size_t)(p & 0xFFFF) * H + lane],
                   exps[off + i] * rden[(p >> 16) & 255], acc);
    }
    out[(size_t)n * H + lane] = acc;
}

extern "C" void kernel_launch(void* const* d_in, const int* in_sizes, int n_in,
                              void* d_out, int out_size, void* d_ws, size_t ws_size,
                              hipStream_t stream)
{
    const float* x   = (const float*)d_in[0];
    const float* Wq  = (const float*)d_in[1];
    const float* bq  = (const float*)d_in[2];
    const float* Wk  = (const float*)d_in[3];
    const float* bk  = (const float*)d_in[4];
    const float* Wv  = (const float*)d_in[5];
    const float* bv  = (const float*)d_in[6];
    const int* ei    = (const int*)d_in[7];
    const int* batch = (const int*)d_in[8];

    const int N = in_sizes[8];        // 50000
    const int E = in_sizes[7] / 2;    // 800000
    const int EP = E + 3 * N + 16;    // padded edge-slot capacity

    float*    q       = (float*)d_ws;
    float*    k       = q + (size_t)N * H;
    float*    v       = k + (size_t)N * H;
    float*    exps    = v + (size_t)N * H;
    unsigned* epack   = (unsigned*)(exps + EP);
    int*      counts  = (int*)(epack + EP);
    int*      offsets = counts + N;
    int*      cursor  = offsets + N;
    int*      bsum    = cursor + N;
    float*    denom8  = (float*)(bsum + 64);
    int*      wq      = (int*)(denom8 + 8 * NSEG);   // 8 work-queue heads
    int*      counts8 = wq + 16;                     // 8N ints

    // one memset covers denom8 (8 KB) + wq (64 B)
    hipMemsetAsync(denom8, 0, 8 * NSEG * sizeof(float) + 16 * sizeof(int), stream);

    const int NT    = (N + MB - 1) / MB;      // 782 row tiles
    const int nspan = (N + 7) / 8;            // dst-range span per class
    const int NRCH  = (E + RCH - 1) / RCH;    // 196 reorder chunks
    const int NBSC  = (N + SCB - 1) / SCB;    // 25 scan blocks

    hist8_kernel<<<64, 1024, 0, stream>>>(ei, counts8, N, E, nspan);

    qkv_mfma<<<256, 768, 0, stream>>>(
        x, Wq, Wk, Wv, bq, bk, bv, q, k, v, N, NT);

    scanA<<<NBSC, 256, 0, stream>>>(counts8, counts, offsets, bsum, N);
    scanB<<<1, 64, 0, stream>>>(bsum, NBSC);
    scanC<<<NBSC, 256, 0, stream>>>(bsum, offsets, cursor, N);

    reorder_kernel<<<2048, 256, 0, stream>>>(
        ei, batch, cursor, epack, wq, E, N, nspan, NRCH);

    score_kernel<<<2048, 256, 0, stream>>>(
        q, k, epack, offsets, counts, exps, denom8, N);

    accum_kernel<<<(N + 3) / 4, 256, 0, stream>>>(
        v, exps, epack, offsets, counts, denom8, (float*)d_out, N);
}

// Round 11
// 264.396 us; speedup vs baseline: 1.7065x; 1.7065x over previous
//
#include <hip/hip_runtime.h>

#define H    64
#define F    256
#define NSEG 256
#define SCB  2048   // scan elements per block
#define MB   64     // qkv node rows per tile
#define KC   64     // qkv K chunk
#define NSPAN_MAX 8192

typedef float          f32x4v __attribute__((ext_vector_type(4)));
typedef short          bf16x8 __attribute__((ext_vector_type(8)));
typedef unsigned short u16x4  __attribute__((ext_vector_type(4)));

// ---------------------------------------------------------------------------
// In-degree histogram: LDS-privatized, zero global atomics (R9-verified).
// Grid = 8 spans x 8 chunks; LDS histogram per block; non-atomic flush to
// counts8[chunk]; scanA sums the 8 copies.
// ---------------------------------------------------------------------------
__global__ __launch_bounds__(1024) void hist8_kernel(
    const int* __restrict__ ei, int* __restrict__ counts8,
    int N, int E, int nspan)
{
    __shared__ int lh[NSPAN_MAX];
    const int p  = blockIdx.x & 7;           // span class
    const int c  = blockIdx.x >> 3;          // edge chunk 0..7
    const int lo = p * nspan;
    const int span = min(N - lo, nspan);
    const int t = threadIdx.x;

    for (int i = t; i < span; i += 1024) lh[i] = 0;
    __syncthreads();

    const int epc = (E + 7) >> 3;            // edges per chunk
    const int e0 = c * epc;
    const int e1 = min(E, e0 + epc);

    if (((E + e0) & 3) == 0) {               // 16B-aligned vector path
        const int nv = (e1 - e0) >> 2;
        for (int i = t; i < nv; i += 1024) {
            const int4 d4 = *(const int4*)(ei + E + e0 + i * 4);
            int d;
            d = min(max(d4.x, 0), N - 1) - lo; if ((unsigned)d < (unsigned)span) atomicAdd(&lh[d], 1);
            d = min(max(d4.y, 0), N - 1) - lo; if ((unsigned)d < (unsigned)span) atomicAdd(&lh[d], 1);
            d = min(max(d4.z, 0), N - 1) - lo; if ((unsigned)d < (unsigned)span) atomicAdd(&lh[d], 1);
            d = min(max(d4.w, 0), N - 1) - lo; if ((unsigned)d < (unsigned)span) atomicAdd(&lh[d], 1);
        }
        for (int e = e0 + nv * 4 + t; e < e1; e += 1024) {
            const int d = min(max(ei[E + e], 0), N - 1) - lo;
            if ((unsigned)d < (unsigned)span) atomicAdd(&lh[d], 1);
        }
    } else {
        for (int e = e0 + t; e < e1; e += 1024) {
            const int d = min(max(ei[E + e], 0), N - 1) - lo;
            if ((unsigned)d < (unsigned)span) atomicAdd(&lh[d], 1);
        }
    }
    __syncthreads();

    for (int i = t; i < span; i += 1024) counts8[(size_t)c * N + lo + i] = lh[i];
}

// ---------------------------------------------------------------------------
// QKV GEMM, persistent-W + XOR-swizzled LDS (carried from R10; correctness-
// verified there).  No pad, 128B rows, 16B-block index XORed with row&7 ->
// ds_read_b128 spreads over 8 bank-quads 2-way (free per m136).
//   acc += xh*wh + xh*wl + xl*wh    (xl*wl ~ 2^-17 dropped)
// ---------------------------------------------------------------------------
#define CVT_WRITE(buf, rr, cc, val) do {                                      \
    const float ff_[4] = {(val).x, (val).y, (val).z, (val).w};                \
    u16x4 h_, l_;                                                             \
    _Pragma("unroll")                                                         \
    for (int u_ = 0; u_ < 4; ++u_) {                                          \
        unsigned ub_ = __float_as_uint(ff_[u_]);                              \
        h_[u_] = (unsigned short)(ub_ >> 16);                                 \
        float rf_ = ff_[u_] - __uint_as_float(ub_ & 0xFFFF0000u);             \
        l_[u_] = (unsigned short)(__float_as_uint(rf_) >> 16);                \
    }                                                                         \
    const int so_ = (rr) * 64 + (((((cc) >> 1) ^ ((rr) & 7))) << 3)           \
                  + ((cc) & 1) * 4;                                           \
    *(u16x4*)&xs_hi[buf][so_] = h_;                                           \
    *(u16x4*)&xs_lo[buf][so_] = l_;                                           \
} while (0)

__global__ __launch_bounds__(768, 3) void qkv_mfma(
    const float* __restrict__ x,
    const float* __restrict__ Wq, const float* __restrict__ Wk,
    const float* __restrict__ Wv,
    const float* __restrict__ bq, const float* __restrict__ bk,
    const float* __restrict__ bv,
    float* __restrict__ q, float* __restrict__ k, float* __restrict__ v,
    int N, int ntiles)
{
    __shared__ unsigned short xs_hi[2][MB * 64];   // 2 x 8 KB, swizzled
    __shared__ unsigned short xs_lo[2][MB * 64];   // 2 x 8 KB, swizzled

    const int t    = threadIdx.x;
    const int lane = t & 63;
    const int w    = t >> 6;        // 0..11
    const int mat  = w >> 2;        // 0..2  (Q,K,V)
    const int ct   = w & 3;         // 16-col tile
    const int l15  = lane & 15;
    const int quad = lane >> 4;

    const float* Wm   = (mat == 0) ? Wq : (mat == 1) ? Wk : Wv;
    const float* bias = (mat == 0) ? bq : (mat == 1) ? bk : bv;
    float*       dst  = (mat == 0) ? q  : (mat == 1) ? k  : v;
    const int col = ct * 16 + l15;
    const float bb = bias[col];

    // ---- W preload: full-K B fragments in registers, split hi/lo in-reg ---
    bf16x8 Bh[8], Bl[8];
    #pragma unroll
    for (int u = 0; u < 8; ++u) {
        #pragma unroll
        for (int j = 0; j < 8; ++j) {
            const float f = Wm[(size_t)(u * 32 + quad * 8 + j) * H + col];
            const unsigned ub = __float_as_uint(f);
            Bh[u][j] = (short)(ub >> 16);
            const float rf = f - __uint_as_float(ub & 0xFFFF0000u);
            Bl[u][j] = (short)(__float_as_uint(rf) >> 16);
        }
    }

    // staging slots: 1024 float4 per chunk; thread t does slot t (always)
    // and slot t+768 (t<256).  (t+768)&15 == t&15 since 768 % 16 == 0.
    const int r0 = t >> 4;
    const int c0 = t & 15;
    const int r1 = (t + 768) >> 4;

    // swizzled read offsets (row & 7 == l15 & 7)
    const int swz = (l15 & 7);

    #pragma unroll 1
    for (int tile = blockIdx.x; tile < ntiles; tile += gridDim.x) {
        const int block0 = tile * MB;

        f32x4v acc[4];
        #pragma unroll
        for (int i = 0; i < 4; ++i) acc[i] = (f32x4v)0.f;

        // ---- prologue: chunk 0 into buffer 0 ----
        float4 pv0, pv1;
        pv0 = *(const float4*)(x + (size_t)min(block0 + r0, N - 1) * F + c0 * 4);
        if (t < 256)
            pv1 = *(const float4*)(x + (size_t)min(block0 + r1, N - 1) * F + c0 * 4);
        CVT_WRITE(0, r0, c0, pv0);
        if (t < 256) CVT_WRITE(0, r1, c0, pv1);

        #pragma unroll
        for (int c = 0; c < 4; ++c) {
            __syncthreads();          // buf[c&1] writes visible to all waves

            // issue next chunk's loads EARLY (consumed after the MFMAs)
            if (c < 3) {
                const int kb = (c + 1) * KC;
                pv0 = *(const float4*)(x + (size_t)min(block0 + r0, N - 1) * F + kb + c0 * 4);
                if (t < 256)
                    pv1 = *(const float4*)(x + (size_t)min(block0 + r1, N - 1) * F + kb + c0 * 4);
            }

            // MFMA burst on buf[c&1]; B frags from registers (u = c*2+sk)
            #pragma unroll
            for (int sk = 0; sk < 2; ++sk) {
                const int u = c * 2 + sk;
                #pragma unroll
                for (int mt = 0; mt < 4; ++mt) {
                    const int row = mt * 16 + l15;
                    const int ao  = row * 64 + (((sk * 4 + quad) ^ swz) << 3);
                    const bf16x8 ah = *(const bf16x8*)&xs_hi[c & 1][ao];
                    const bf16x8 al = *(const bf16x8*)&xs_lo[c & 1][ao];
                    f32x4v a = acc[mt];
                    a = __builtin_amdgcn_mfma_f32_16x16x32_bf16(ah, Bh[u], a, 0, 0, 0);
                    a = __builtin_amdgcn_mfma_f32_16x16x32_bf16(ah, Bl[u], a, 0, 0, 0);
                    a = __builtin_amdgcn_mfma_f32_16x16x32_bf16(al, Bh[u], a, 0, 0, 0);
                    acc[mt] = a;
                }
            }

            // convert + write next chunk into the other buffer (WAR-safe:
            // buf[nxt] last read in chunk c-1, all waves past top-of-c barrier)
            if (c < 3) {
                const int nb = (c & 1) ^ 1;
                CVT_WRITE(nb, r0, c0, pv0);
                if (t < 256) CVT_WRITE(nb, r1, c0, pv1);
            }
        }

        // epilogue: C layout col = lane&15, row = quad*4 + reg (m89-verified)
        #pragma unroll
        for (int mt = 0; mt < 4; ++mt) {
            #pragma unroll
            for (int r = 0; r < 4; ++r) {
                const int node = block0 + mt * 16 + quad * 4 + r;
                if (node < N)
                    dst[(size_t)node * H + col] = acc[mt][r] + bb;
            }
        }
    }
}

// ---------------------------------------------------------------------------
// Scan phase A/B/C: exclusive scan of padded (x4) per-node counts.
// scanA sums the 8 per-chunk histogram copies and emits merged counts.
// ---------------------------------------------------------------------------
__global__ __launch_bounds__(256) void scanA(
    const int* __restrict__ counts8, int* __restrict__ counts,
    int* __restrict__ offsets, int* __restrict__ bsum, int n)
{
    __shared__ int ps[256];
    const int t = threadIdx.x;
    const int i0 = blockIdx.x * SCB + t * 8;
    int loc[8];
    int s = 0;
    #pragma unroll
    for (int u = 0; u < 8; ++u) {
        int i = i0 + u;
        int c = 0;
        if (i < n) {
            #pragma unroll
            for (int p = 0; p < 8; ++p) c += counts8[(size_t)p * n + i];
            counts[i] = c;
            c = (c + 3) & ~3;
        }
        loc[u] = s; s += c;
    }
    ps[t] = s;
    __syncthreads();
    for (int off = 1; off < 256; off <<= 1) {
        int a = (t >= off) ? ps[t - off] : 0;
        __syncthreads();
        ps[t] += a;
        __syncthreads();
    }
    const int base = ps[t] - s;
    #pragma unroll
    for (int u = 0; u < 8; ++u) {
        int i = i0 + u;
        if (i < n) offsets[i] = base + loc[u];
    }
    if (t == 255) bsum[blockIdx.x] = ps[255];
}

__global__ void scanB(int* __restrict__ bsum, int nb)
{
    // single-wave shuffle exclusive scan (nb <= 64)
    const int t = threadIdx.x;
    int v = (t < nb) ? bsum[t] : 0;
    int inc = v;
    #pragma unroll
    for (int off = 1; off < 64; off <<= 1) {
        int u = __shfl_up(inc, off, 64);
        if (t >= off) inc += u;
    }
    if (t < nb) bsum[t] = inc - v;   // exclusive
}

__global__ __launch_bounds__(256) void scanC(
    const int* __restrict__ bsum, int* __restrict__ offsets,
    int* __restrict__ cursor, int n)
{
    const int i0 = blockIdx.x * SCB + threadIdx.x * 8;
    const int add = bsum[blockIdx.x];
    #pragma unroll
    for (int u = 0; u < 8; ++u) {
        int i = i0 + u;
        if (i < n) { int o = offsets[i] + add; offsets[i] = o; cursor[i] = o; }
    }
}

// ---------------------------------------------------------------------------
// Reorder edges into dst-node order, dst-range partitioned by blockIdx&7
// (R9-measured-best: 41us).  R10's true-XCD work-queue variant regressed
// 5.6x (serialized classes) and proved the residual epack write-backs are
// NOT cross-XCD bouncing -- this is the verified-best scatter form.
// pack = src(16b) | seg(8b)<<16.
// ---------------------------------------------------------------------------
__global__ __launch_bounds__(256) void reorder_kernel(
    const int* __restrict__ ei, const int* __restrict__ batch,
    int* __restrict__ cursor, unsigned* __restrict__ epack,
    int E, int N, int nspan)
{
    const int p  = blockIdx.x & 7;
    const int ci = blockIdx.x >> 3;
    const int lo = p * nspan;
    const int hi = min(N, lo + nspan);
    const int e0 = ci * 1024 + threadIdx.x * 4;

    int d[4];
    if (e0 + 3 < E) {
        const int4 d4 = *(const int4*)(ei + E + e0);
        d[0] = d4.x; d[1] = d4.y; d[2] = d4.z; d[3] = d4.w;
    } else {
        #pragma unroll
        for (int u = 0; u < 4; ++u)
            d[u] = (e0 + u < E) ? ei[E + e0 + u] : -1;   // -1: never in span
    }

    #pragma unroll
    for (int u = 0; u < 4; ++u) {
        const int dst = min(max(d[u], 0), N - 1);
        if (d[u] >= 0 && dst >= lo && dst < hi) {
            int src = ei[e0 + u];
            src = min(max(src, 0), N - 1);
            int seg = batch[src];
            seg = min(max(seg, 0), NSEG - 1);
            const int pos = atomicAdd(&cursor[dst], 1);
            epack[pos] = (unsigned)src | ((unsigned)seg << 16);
        }
    }
}

// ---------------------------------------------------------------------------
// Score: persistent grid, one wave per dst node; q[dst] in registers across
// its edges; 4 edges in flight (16-lane groups, float4 k gathers, 4-step
// shuffle reduce).  Per-block LDS denom histogram flushed once into the
// blockIdx&7 denom copy (R6-R9 verified form).
// ---------------------------------------------------------------------------
__global__ __launch_bounds__(256) void score_kernel(
    const float* __restrict__ q, const float* __restrict__ k,
    const unsigned* __restrict__ epack,
    const int* __restrict__ offsets, const int* __restrict__ counts,
    float* __restrict__ exps, float* __restrict__ denom8, int N)
{
    __shared__ float sden[NSEG];
    const int t = threadIdx.x;
    sden[t] = 0.f;
    __syncthreads();

    const int lane16 = t & 15;
    const int grp    = (t >> 4) & 3;
    const int wave   = t >> 6;
    const int nwaves = gridDim.x * 4;

    const float4* q4 = (const float4*)q;
    const float4* k4 = (const float4*)k;

    for (int n = blockIdx.x * 4 + wave; n < N; n += nwaves) {
        const int off = offsets[n];
        const int cnt = counts[n];
        if (cnt == 0) continue;
        const float4 qv = q4[(size_t)n * 16 + lane16];
        for (int i = grp; i < cnt; i += 4) {
            const int pos = off + i;
            const unsigned p = epack[pos];
            const int src = p & 0xFFFF;
            const float4 kv = k4[(size_t)src * 16 + lane16];
            float d = kv.x * qv.x + kv.y * qv.y + kv.z * qv.z + kv.w * qv.w;
            d += __shfl_xor(d, 1, 64);
            d += __shfl_xor(d, 2, 64);
            d += __shfl_xor(d, 4, 64);
            d += __shfl_xor(d, 8, 64);
            if (lane16 == 0) {
                float ex = __expf(d * 0.125f);
                exps[pos] = ex;
                atomicAdd(&sden[(p >> 16) & 255], ex);
            }
        }
    }
    __syncthreads();
    float ds = sden[t];
    if (ds != 0.f) atomicAdd(&denom8[(blockIdx.x & 7) * NSEG + t], ds);
}

// ---------------------------------------------------------------------------
// Accumulate: one wave per dst node, lane = feature, register accumulator,
// zero atomics.  LDS reciprocal table built by summing the 8 denom copies.
// ---------------------------------------------------------------------------
__global__ __launch_bounds__(256) void accum_kernel(
    const float* __restrict__ v, const float* __restrict__ exps,
    const unsigned* __restrict__ epack,
    const int* __restrict__ offsets, const int* __restrict__ counts,
    const float* __restrict__ denom8, float* __restrict__ out, int N)
{
    __shared__ float rden[NSEG];
    const int t = threadIdx.x;
    {
        float dsum = 0.f;
        #pragma unroll
        for (int p = 0; p < 8; ++p) dsum += denom8[p * NSEG + t];
        rden[t] = 1.0f / (dsum + 1e-6f);
    }
    __syncthreads();

    const int lane = t & 63;
    const int wave = t >> 6;
    const int n = blockIdx.x * 4 + wave;
    if (n >= N) return;

    const int off = offsets[n];
    const int cnt = counts[n];

    float acc = 0.f;
    int i = 0;
    for (; i + 8 <= cnt; i += 8) {
        const uint4  pa = *(const uint4*)(epack + off + i);
        const uint4  pb = *(const uint4*)(epack + off + i + 4);
        const float4 ea = *(const float4*)(exps + off + i);
        const float4 eb = *(const float4*)(exps + off + i + 4);
        const float v0 = v[(size_t)(pa.x & 0xFFFF) * H + lane];
        const float v1 = v[(size_t)(pa.y & 0xFFFF) * H + lane];
        const float v2 = v[(size_t)(pa.z & 0xFFFF) * H + lane];
        const float v3 = v[(size_t)(pa.w & 0xFFFF) * H + lane];
        const float v4_ = v[(size_t)(pb.x & 0xFFFF) * H + lane];
        const float v5 = v[(size_t)(pb.y & 0xFFFF) * H + lane];
        const float v6 = v[(size_t)(pb.z & 0xFFFF) * H + lane];
        const float v7 = v[(size_t)(pb.w & 0xFFFF) * H + lane];
        acc = fmaf(v0, ea.x * rden[(pa.x >> 16) & 255], acc);
        acc = fmaf(v1, ea.y * rden[(pa.y >> 16) & 255], acc);
        acc = fmaf(v2, ea.z * rden[(pa.z >> 16) & 255], acc);
        acc = fmaf(v3, ea.w * rden[(pa.w >> 16) & 255], acc);
        acc = fmaf(v4_, eb.x * rden[(pb.x >> 16) & 255], acc);
        acc = fmaf(v5, eb.y * rden[(pb.y >> 16) & 255], acc);
        acc = fmaf(v6, eb.z * rden[(pb.z >> 16) & 255], acc);
        acc = fmaf(v7, eb.w * rden[(pb.w >> 16) & 255], acc);
    }
    for (; i + 4 <= cnt; i += 4) {
        const uint4  pp = *(const uint4*)(epack + off + i);
        const float4 ee = *(const float4*)(exps + off + i);
        const float v0 = v[(size_t)(pp.x & 0xFFFF) * H + lane];
        const float v1 = v[(size_t)(pp.y & 0xFFFF) * H + lane];
        const float v2 = v[(size_t)(pp.z & 0xFFFF) * H + lane];
        const float v3 = v[(size_t)(pp.w & 0xFFFF) * H + lane];
        acc = fmaf(v0, ee.x * rden[(pp.x >> 16) & 255], acc);
        acc = fmaf(v1, ee.y * rden[(pp.y >> 16) & 255], acc);
        acc = fmaf(v2, ee.z * rden[(pp.z >> 16) & 255], acc);
        acc = fmaf(v3, ee.w * rden[(pp.w >> 16) & 255], acc);
    }
    for (; i < cnt; ++i) {
        const unsigned p = epack[off + i];
        acc = fmaf(v[(size_t)(p & 0xFFFF) * H + lane],
                   exps[off + i] * rden[(p >> 16) & 255], acc);
    }
    out[(size_t)n * H + lane] = acc;
}

extern "C" void kernel_launch(void* const* d_in, const int* in_sizes, int n_in,
                              void* d_out, int out_size, void* d_ws, size_t ws_size,
                              hipStream_t stream)
{
    const float* x   = (const float*)d_in[0];
    const float* Wq  = (const float*)d_in[1];
    const float* bq  = (const float*)d_in[2];
    const float* Wk  = (const float*)d_in[3];
    const float* bk  = (const float*)d_in[4];
    const float* Wv  = (const float*)d_in[5];
    const float* bv  = (const float*)d_in[6];
    const int* ei    = (const int*)d_in[7];
    const int* batch = (const int*)d_in[8];

    const int N = in_sizes[8];        // 50000
    const int E = in_sizes[7] / 2;    // 800000
    const int EP = E + 3 * N + 16;    // padded edge-slot capacity

    float*    q       = (float*)d_ws;
    float*    k       = q + (size_t)N * H;
    float*    v       = k + (size_t)N * H;
    float*    exps    = v + (size_t)N * H;
    unsigned* epack   = (unsigned*)(exps + EP);
    int*      counts  = (int*)(epack + EP);
    int*      offsets = counts + N;
    int*      cursor  = offsets + N;
    int*      bsum    = cursor + N;
    float*    denom8  = (float*)(bsum + 64);
    int*      counts8 = (int*)(denom8 + 8 * NSEG);   // 8N ints

    hipMemsetAsync(denom8, 0, 8 * NSEG * sizeof(float), stream);

    const int NT    = (N + MB - 1) / MB;     // 782 row tiles
    const int NC    = (E + 1023) / 1024;     // 782 edge chunks
    const int nspan = (N + 7) / 8;           // dst-range span per class
    const int NBSC  = (N + SCB - 1) / SCB;   // 25 scan blocks

    hist8_kernel<<<64, 1024, 0, stream>>>(ei, counts8, N, E, nspan);

    qkv_mfma<<<256, 768, 0, stream>>>(
        x, Wq, Wk, Wv, bq, bk, bv, q, k, v, N, NT);

    scanA<<<NBSC, 256, 0, stream>>>(counts8, counts, offsets, bsum, N);
    scanB<<<1, 64, 0, stream>>>(bsum, NBSC);
    scanC<<<NBSC, 256, 0, stream>>>(bsum, offsets, cursor, N);

    reorder_kernel<<<8 * NC, 256, 0, stream>>>(
        ei, batch, cursor, epack, E, N, nspan);

    score_kernel<<<2048, 256, 0, stream>>>(
        q, k, epack, offsets, counts, exps, denom8, N);

    accum_kernel<<<(N + 3) / 4, 256, 0, stream>>>(
        v, exps, epack, offsets, counts, denom8, (float*)d_out, N);
}

// Round 12
// 260.132 us; speedup vs baseline: 1.7345x; 1.0164x over previous
//
#include <hip/hip_runtime.h>

#define H    64
#define F    256
#define NSEG 256
#define SCB  2048   // scan elements per block
#define MB   64     // qkv node rows per tile
#define KC   64     // qkv K chunk
#define NSPAN_MAX 8192

typedef float          f32x4v __attribute__((ext_vector_type(4)));
typedef short          bf16x8 __attribute__((ext_vector_type(8)));
typedef unsigned short u16x4  __attribute__((ext_vector_type(4)));

// ---------------------------------------------------------------------------
// In-degree histogram: LDS-privatized, zero global atomics (R9-verified).
// Grid = 8 spans x 8 chunks; LDS histogram per block; non-atomic flush to
// counts8[chunk]; scanA sums the 8 copies.
// ---------------------------------------------------------------------------
__global__ __launch_bounds__(1024) void hist8_kernel(
    const int* __restrict__ ei, int* __restrict__ counts8,
    int N, int E, int nspan)
{
    __shared__ int lh[NSPAN_MAX];
    const int p  = blockIdx.x & 7;           // span class
    const int c  = blockIdx.x >> 3;          // edge chunk 0..7
    const int lo = p * nspan;
    const int span = min(N - lo, nspan);
    const int t = threadIdx.x;

    for (int i = t; i < span; i += 1024) lh[i] = 0;
    __syncthreads();

    const int epc = (E + 7) >> 3;            // edges per chunk
    const int e0 = c * epc;
    const int e1 = min(E, e0 + epc);

    if (((E + e0) & 3) == 0) {               // 16B-aligned vector path
        const int nv = (e1 - e0) >> 2;
        for (int i = t; i < nv; i += 1024) {
            const int4 d4 = *(const int4*)(ei + E + e0 + i * 4);
            int d;
            d = min(max(d4.x, 0), N - 1) - lo; if ((unsigned)d < (unsigned)span) atomicAdd(&lh[d], 1);
            d = min(max(d4.y, 0), N - 1) - lo; if ((unsigned)d < (unsigned)span) atomicAdd(&lh[d], 1);
            d = min(max(d4.z, 0), N - 1) - lo; if ((unsigned)d < (unsigned)span) atomicAdd(&lh[d], 1);
            d = min(max(d4.w, 0), N - 1) - lo; if ((unsigned)d < (unsigned)span) atomicAdd(&lh[d], 1);
        }
        for (int e = e0 + nv * 4 + t; e < e1; e += 1024) {
            const int d = min(max(ei[E + e], 0), N - 1) - lo;
            if ((unsigned)d < (unsigned)span) atomicAdd(&lh[d], 1);
        }
    } else {
        for (int e = e0 + t; e < e1; e += 1024) {
            const int d = min(max(ei[E + e], 0), N - 1) - lo;
            if ((unsigned)d < (unsigned)span) atomicAdd(&lh[d], 1);
        }
    }
    __syncthreads();

    for (int i = t; i < span; i += 1024) counts8[(size_t)c * N + lo + i] = lh[i];
}

// ---------------------------------------------------------------------------
// QKV GEMM, persistent-W + XOR-swizzled LDS (R10/R11-verified).
//   acc += xh*wh + xh*wl + xl*wh    (xl*wl ~ 2^-17 dropped)
// ---------------------------------------------------------------------------
#define CVT_WRITE(buf, rr, cc, val) do {                                      \
    const float ff_[4] = {(val).x, (val).y, (val).z, (val).w};                \
    u16x4 h_, l_;                                                             \
    _Pragma("unroll")                                                         \
    for (int u_ = 0; u_ < 4; ++u_) {                                          \
        unsigned ub_ = __float_as_uint(ff_[u_]);                              \
        h_[u_] = (unsigned short)(ub_ >> 16);                                 \
        float rf_ = ff_[u_] - __uint_as_float(ub_ & 0xFFFF0000u);             \
        l_[u_] = (unsigned short)(__float_as_uint(rf_) >> 16);                \
    }                                                                         \
    const int so_ = (rr) * 64 + (((((cc) >> 1) ^ ((rr) & 7))) << 3)           \
                  + ((cc) & 1) * 4;                                           \
    *(u16x4*)&xs_hi[buf][so_] = h_;                                           \
    *(u16x4*)&xs_lo[buf][so_] = l_;                                           \
} while (0)

__global__ __launch_bounds__(768, 3) void qkv_mfma(
    const float* __restrict__ x,
    const float* __restrict__ Wq, const float* __restrict__ Wk,
    const float* __restrict__ Wv,
    const float* __restrict__ bq, const float* __restrict__ bk,
    const float* __restrict__ bv,
    float* __restrict__ q, float* __restrict__ k, float* __restrict__ v,
    int N, int ntiles)
{
    __shared__ unsigned short xs_hi[2][MB * 64];   // 2 x 8 KB, swizzled
    __shared__ unsigned short xs_lo[2][MB * 64];   // 2 x 8 KB, swizzled

    const int t    = threadIdx.x;
    const int lane = t & 63;
    const int w    = t >> 6;        // 0..11
    const int mat  = w >> 2;        // 0..2  (Q,K,V)
    const int ct   = w & 3;         // 16-col tile
    const int l15  = lane & 15;
    const int quad = lane >> 4;

    const float* Wm   = (mat == 0) ? Wq : (mat == 1) ? Wk : Wv;
    const float* bias = (mat == 0) ? bq : (mat == 1) ? bk : bv;
    float*       dst  = (mat == 0) ? q  : (mat == 1) ? k  : v;
    const int col = ct * 16 + l15;
    const float bb = bias[col];

    // ---- W preload: full-K B fragments in registers, split hi/lo in-reg ---
    bf16x8 Bh[8], Bl[8];
    #pragma unroll
    for (int u = 0; u < 8; ++u) {
        #pragma unroll
        for (int j = 0; j < 8; ++j) {
            const float f = Wm[(size_t)(u * 32 + quad * 8 + j) * H + col];
            const unsigned ub = __float_as_uint(f);
            Bh[u][j] = (short)(ub >> 16);
            const float rf = f - __uint_as_float(ub & 0xFFFF0000u);
            Bl[u][j] = (short)(__float_as_uint(rf) >> 16);
        }
    }

    // staging slots: 1024 float4 per chunk; thread t does slot t (always)
    // and slot t+768 (t<256).  (t+768)&15 == t&15 since 768 % 16 == 0.
    const int r0 = t >> 4;
    const int c0 = t & 15;
    const int r1 = (t + 768) >> 4;

    // swizzled read offsets (row & 7 == l15 & 7)
    const int swz = (l15 & 7);

    #pragma unroll 1
    for (int tile = blockIdx.x; tile < ntiles; tile += gridDim.x) {
        const int block0 = tile * MB;

        f32x4v acc[4];
        #pragma unroll
        for (int i = 0; i < 4; ++i) acc[i] = (f32x4v)0.f;

        // ---- prologue: chunk 0 into buffer 0 ----
        float4 pv0, pv1;
        pv0 = *(const float4*)(x + (size_t)min(block0 + r0, N - 1) * F + c0 * 4);
        if (t < 256)
            pv1 = *(const float4*)(x + (size_t)min(block0 + r1, N - 1) * F + c0 * 4);
        CVT_WRITE(0, r0, c0, pv0);
        if (t < 256) CVT_WRITE(0, r1, c0, pv1);

        #pragma unroll
        for (int c = 0; c < 4; ++c) {
            __syncthreads();          // buf[c&1] writes visible to all waves

            // issue next chunk's loads EARLY (consumed after the MFMAs)
            if (c < 3) {
                const int kb = (c + 1) * KC;
                pv0 = *(const float4*)(x + (size_t)min(block0 + r0, N - 1) * F + kb + c0 * 4);
                if (t < 256)
                    pv1 = *(const float4*)(x + (size_t)min(block0 + r1, N - 1) * F + kb + c0 * 4);
            }

            // MFMA burst on buf[c&1]; B frags from registers (u = c*2+sk)
            #pragma unroll
            for (int sk = 0; sk < 2; ++sk) {
                const int u = c * 2 + sk;
                #pragma unroll
                for (int mt = 0; mt < 4; ++mt) {
                    const int row = mt * 16 + l15;
                    const int ao  = row * 64 + (((sk * 4 + quad) ^ swz) << 3);
                    const bf16x8 ah = *(const bf16x8*)&xs_hi[c & 1][ao];
                    const bf16x8 al = *(const bf16x8*)&xs_lo[c & 1][ao];
                    f32x4v a = acc[mt];
                    a = __builtin_amdgcn_mfma_f32_16x16x32_bf16(ah, Bh[u], a, 0, 0, 0);
                    a = __builtin_amdgcn_mfma_f32_16x16x32_bf16(ah, Bl[u], a, 0, 0, 0);
                    a = __builtin_amdgcn_mfma_f32_16x16x32_bf16(al, Bh[u], a, 0, 0, 0);
                    acc[mt] = a;
                }
            }

            // convert + write next chunk into the other buffer (WAR-safe:
            // buf[nxt] last read in chunk c-1, all waves past top-of-c barrier)
            if (c < 3) {
                const int nb = (c & 1) ^ 1;
                CVT_WRITE(nb, r0, c0, pv0);
                if (t < 256) CVT_WRITE(nb, r1, c0, pv1);
            }
        }

        // epilogue: C layout col = lane&15, row = quad*4 + reg (m89-verified)
        #pragma unroll
        for (int mt = 0; mt < 4; ++mt) {
            #pragma unroll
            for (int r = 0; r < 4; ++r) {
                const int node = block0 + mt * 16 + quad * 4 + r;
                if (node < N)
                    dst[(size_t)node * H + col] = acc[mt][r] + bb;
            }
        }
    }
}

// ---------------------------------------------------------------------------
// Scan phase A/B/C: exclusive scan of padded (x4) per-node counts.
// scanA sums the 8 per-chunk histogram copies and emits merged counts.
// ---------------------------------------------------------------------------
__global__ __launch_bounds__(256) void scanA(
    const int* __restrict__ counts8, int* __restrict__ counts,
    int* __restrict__ offsets, int* __restrict__ bsum, int n)
{
    __shared__ int ps[256];
    const int t = threadIdx.x;
    const int i0 = blockIdx.x * SCB + t * 8;
    int loc[8];
    int s = 0;
    #pragma unroll
    for (int u = 0; u < 8; ++u) {
        int i = i0 + u;
        int c = 0;
        if (i < n) {
            #pragma unroll
            for (int p = 0; p < 8; ++p) c += counts8[(size_t)p * n + i];
            counts[i] = c;
            c = (c + 3) & ~3;
        }
        loc[u] = s; s += c;
    }
    ps[t] = s;
    __syncthreads();
    for (int off = 1; off < 256; off <<= 1) {
        int a = (t >= off) ? ps[t - off] : 0;
        __syncthreads();
        ps[t] += a;
        __syncthreads();
    }
    const int base = ps[t] - s;
    #pragma unroll
    for (int u = 0; u < 8; ++u) {
        int i = i0 + u;
        if (i < n) offsets[i] = base + loc[u];
    }
    if (t == 255) bsum[blockIdx.x] = ps[255];
}

__global__ void scanB(int* __restrict__ bsum, int nb)
{
    // single-wave shuffle exclusive scan (nb <= 64)
    const int t = threadIdx.x;
    int v = (t < nb) ? bsum[t] : 0;
    int inc = v;
    #pragma unroll
    for (int off = 1; off < 64; off <<= 1) {
        int u = __shfl_up(inc, off, 64);
        if (t >= off) inc += u;
    }
    if (t < nb) bsum[t] = inc - v;   // exclusive
}

__global__ __launch_bounds__(256) void scanC(
    const int* __restrict__ bsum, int* __restrict__ offsets,
    int* __restrict__ cursor, int n)
{
    const int i0 = blockIdx.x * SCB + threadIdx.x * 8;
    const int add = bsum[blockIdx.x];
    #pragma unroll
    for (int u = 0; u < 8; ++u) {
        int i = i0 + u;
        if (i < n) { int o = offsets[i] + add; offsets[i] = o; cursor[i] = o; }
    }
}

// ---------------------------------------------------------------------------
// Reorder edges into dst-node order, dst-range partitioned by blockIdx&7
// (R9/R11-measured-best form).  pack = src(16b) | seg(8b)<<16.
// ---------------------------------------------------------------------------
__global__ __launch_bounds__(256) void reorder_kernel(
    const int* __restrict__ ei, const int* __restrict__ batch,
    int* __restrict__ cursor, unsigned* __restrict__ epack,
    int E, int N, int nspan)
{
    const int p  = blockIdx.x & 7;
    const int ci = blockIdx.x >> 3;
    const int lo = p * nspan;
    const int hi = min(N, lo + nspan);
    const int e0 = ci * 1024 + threadIdx.x * 4;

    int d[4];
    if (e0 + 3 < E) {
        const int4 d4 = *(const int4*)(ei + E + e0);
        d[0] = d4.x; d[1] = d4.y; d[2] = d4.z; d[3] = d4.w;
    } else {
        #pragma unroll
        for (int u = 0; u < 4; ++u)
            d[u] = (e0 + u < E) ? ei[E + e0 + u] : -1;   // -1: never in span
    }

    #pragma unroll
    for (int u = 0; u < 4; ++u) {
        const int dst = min(max(d[u], 0), N - 1);
        if (d[u] >= 0 && dst >= lo && dst < hi) {
            int src = ei[e0 + u];
            src = min(max(src, 0), N - 1);
            int seg = batch[src];
            seg = min(max(seg, 0), NSEG - 1);
            const int pos = atomicAdd(&cursor[dst], 1);
            epack[pos] = (unsigned)src | ((unsigned)seg << 16);
        }
    }
}

// ---------------------------------------------------------------------------
// Score v2: 4-edge ILP batches.  R11 post-mortem: serial per-group edge loop
// left only 4 edges/wave in flight (dependent epack->k->dot->exp chain per
// edge; all pipes <30% at 62% occupancy = latency-bound).  Now each 16-lane
// group takes 4 consecutive edges per iteration: one uint4 epack read
// (offsets are x4-padded -> 16B-aligned; over-read slots allocated, masked
// before use), 4 INDEPENDENT k-row gathers (src clamped so loads stay
// unconditional), 4 interleaved dot+shuffle chains -> 16 edges in flight
// per wave.  Same per-edge numerics and write set as R11.
// ---------------------------------------------------------------------------
__global__ __launch_bounds__(256) void score_kernel(
    const float* __restrict__ q, const float* __restrict__ k,
    const unsigned* __restrict__ epack,
    const int* __restrict__ offsets, const int* __restrict__ counts,
    float* __restrict__ exps, float* __restrict__ denom8, int N)
{
    __shared__ float sden[NSEG];
    const int t = threadIdx.x;
    sden[t] = 0.f;
    __syncthreads();

    const int lane16 = t & 15;
    const int grp    = (t >> 4) & 3;
    const int wave   = t >> 6;
    const int nwaves = gridDim.x * 4;

    const float4* q4 = (const float4*)q;
    const float4* k4 = (const float4*)k;

    for (int n = blockIdx.x * 4 + wave; n < N; n += nwaves) {
        const int off = offsets[n];
        const int cnt = counts[n];
        if (cnt == 0) continue;
        const float4 qv = q4[(size_t)n * 16 + lane16];
        for (int i0 = grp * 4; i0 < cnt; i0 += 16) {
            const uint4 pp = *(const uint4*)(epack + off + i0);   // 16B-aligned
            const unsigned pk[4] = {pp.x, pp.y, pp.z, pp.w};
            const int rem = cnt - i0;
            // 4 independent k-row gathers (clamped; garbage lanes masked later)
            float4 kv[4];
            #pragma unroll
            for (int u = 0; u < 4; ++u) {
                const int src = min((int)(pk[u] & 0xFFFF), N - 1);
                kv[u] = k4[(size_t)src * 16 + lane16];
            }
            // 4 interleaved dot + 4-step shuffle reduce chains
            float d[4];
            #pragma unroll
            for (int u = 0; u < 4; ++u) {
                float dd = kv[u].x * qv.x + kv[u].y * qv.y
                         + kv[u].z * qv.z + kv[u].w * qv.w;
                dd += __shfl_xor(dd, 1, 64);
                dd += __shfl_xor(dd, 2, 64);
                dd += __shfl_xor(dd, 4, 64);
                dd += __shfl_xor(dd, 8, 64);
                d[u] = dd;
            }
            if (lane16 == 0) {
                #pragma unroll
                for (int u = 0; u < 4; ++u) {
                    if (u < rem) {
                        const float ex = __expf(d[u] * 0.125f);
                        exps[off + i0 + u] = ex;
                        atomicAdd(&sden[(pk[u] >> 16) & 255], ex);
                    }
                }
            }
        }
    }
    __syncthreads();
    float ds = sden[t];
    if (ds != 0.f) atomicAdd(&denom8[(blockIdx.x & 7) * NSEG + t], ds);
}

// ---------------------------------------------------------------------------
// Accumulate: one wave per dst node, lane = feature, register accumulator,
// zero atomics.  LDS reciprocal table built by summing the 8 denom copies.
// ---------------------------------------------------------------------------
__global__ __launch_bounds__(256) void accum_kernel(
    const float* __restrict__ v, const float* __restrict__ exps,
    const unsigned* __restrict__ epack,
    const int* __restrict__ offsets, const int* __restrict__ counts,
    const float* __restrict__ denom8, float* __restrict__ out, int N)
{
    __shared__ float rden[NSEG];
    const int t = threadIdx.x;
    {
        float dsum = 0.f;
        #pragma unroll
        for (int p = 0; p < 8; ++p) dsum += denom8[p * NSEG + t];
        rden[t] = 1.0f / (dsum + 1e-6f);
    }
    __syncthreads();

    const int lane = t & 63;
    const int wave = t >> 6;
    const int n = blockIdx.x * 4 + wave;
    if (n >= N) return;

    const int off = offsets[n];
    const int cnt = counts[n];

    float acc = 0.f;
    int i = 0;
    for (; i + 8 <= cnt; i += 8) {
        const uint4  pa = *(const uint4*)(epack + off + i);
        const uint4  pb = *(const uint4*)(epack + off + i + 4);
        const float4 ea = *(const float4*)(exps + off + i);
        const float4 eb = *(const float4*)(exps + off + i + 4);
        const float v0 = v[(size_t)(pa.x & 0xFFFF) * H + lane];
        const float v1 = v[(size_t)(pa.y & 0xFFFF) * H + lane];
        const float v2 = v[(size_t)(pa.z & 0xFFFF) * H + lane];
        const float v3 = v[(size_t)(pa.w & 0xFFFF) * H + lane];
        const float v4_ = v[(size_t)(pb.x & 0xFFFF) * H + lane];
        const float v5 = v[(size_t)(pb.y & 0xFFFF) * H + lane];
        const float v6 = v[(size_t)(pb.z & 0xFFFF) * H + lane];
        const float v7 = v[(size_t)(pb.w & 0xFFFF) * H + lane];
        acc = fmaf(v0, ea.x * rden[(pa.x >> 16) & 255], acc);
        acc = fmaf(v1, ea.y * rden[(pa.y >> 16) & 255], acc);
        acc = fmaf(v2, ea.z * rden[(pa.z >> 16) & 255], acc);
        acc = fmaf(v3, ea.w * rden[(pa.w >> 16) & 255], acc);
        acc = fmaf(v4_, eb.x * rden[(pb.x >> 16) & 255], acc);
        acc = fmaf(v5, eb.y * rden[(pb.y >> 16) & 255], acc);
        acc = fmaf(v6, eb.z * rden[(pb.z >> 16) & 255], acc);
        acc = fmaf(v7, eb.w * rden[(pb.w >> 16) & 255], acc);
    }
    for (; i + 4 <= cnt; i += 4) {
        const uint4  pp = *(const uint4*)(epack + off + i);
        const float4 ee = *(const float4*)(exps + off + i);
        const float v0 = v[(size_t)(pp.x & 0xFFFF) * H + lane];
        const float v1 = v[(size_t)(pp.y & 0xFFFF) * H + lane];
        const float v2 = v[(size_t)(pp.z & 0xFFFF) * H + lane];
        const float v3 = v[(size_t)(pp.w & 0xFFFF) * H + lane];
        acc = fmaf(v0, ee.x * rden[(pp.x >> 16) & 255], acc);
        acc = fmaf(v1, ee.y * rden[(pp.y >> 16) & 255], acc);
        acc = fmaf(v2, ee.z * rden[(pp.z >> 16) & 255], acc);
        acc = fmaf(v3, ee.w * rden[(pp.w >> 16) & 255], acc);
    }
    for (; i < cnt; ++i) {
        const unsigned p = epack[off + i];
        acc = fmaf(v[(size_t)(p & 0xFFFF) * H + lane],
                   exps[off + i] * rden[(p >> 16) & 255], acc);
    }
    out[(size_t)n * H + lane] = acc;
}

extern "C" void kernel_launch(void* const* d_in, const int* in_sizes, int n_in,
                              void* d_out, int out_size, void* d_ws, size_t ws_size,
                              hipStream_t stream)
{
    const float* x   = (const float*)d_in[0];
    const float* Wq  = (const float*)d_in[1];
    const float* bq  = (const float*)d_in[2];
    const float* Wk  = (const float*)d_in[3];
    const float* bk  = (const float*)d_in[4];
    const float* Wv  = (const float*)d_in[5];
    const float* bv  = (const float*)d_in[6];
    const int* ei    = (const int*)d_in[7];
    const int* batch = (const int*)d_in[8];

    const int N = in_sizes[8];        // 50000
    const int E = in_sizes[7] / 2;    // 800000
    const int EP = E + 3 * N + 16;    // padded edge-slot capacity

    float*    q       = (float*)d_ws;
    float*    k       = q + (size_t)N * H;
    float*    v       = k + (size_t)N * H;
    float*    exps    = v + (size_t)N * H;
    unsigned* epack   = (unsigned*)(exps + EP);
    int*      counts  = (int*)(epack + EP);
    int*      offsets = counts + N;
    int*      cursor  = offsets + N;
    int*      bsum    = cursor + N;
    float*    denom8  = (float*)(bsum + 64);
    int*      counts8 = (int*)(denom8 + 8 * NSEG);   // 8N ints

    hipMemsetAsync(denom8, 0, 8 * NSEG * sizeof(float), stream);

    const int NT    = (N + MB - 1) / MB;     // 782 row tiles
    const int NC    = (E + 1023) / 1024;     // 782 edge chunks
    const int nspan = (N + 7) / 8;           // dst-range span per class
    const int NBSC  = (N + SCB - 1) / SCB;   // 25 scan blocks

    hist8_kernel<<<64, 1024, 0, stream>>>(ei, counts8, N, E, nspan);

    qkv_mfma<<<256, 768, 0, stream>>>(
        x, Wq, Wk, Wv, bq, bk, bv, q, k, v, N, NT);

    scanA<<<NBSC, 256, 0, stream>>>(counts8, counts, offsets, bsum, N);
    scanB<<<1, 64, 0, stream>>>(bsum, NBSC);
    scanC<<<NBSC, 256, 0, stream>>>(bsum, offsets, cursor, N);

    reorder_kernel<<<8 * NC, 256, 0, stream>>>(
        ei, batch, cursor, epack, E, N, nspan);

    score_kernel<<<2048, 256, 0, stream>>>(
        q, k, epack, offsets, counts, exps, denom8, N);

    accum_kernel<<<(N + 3) / 4, 256, 0, stream>>>(
        v, exps, epack, offsets, counts, denom8, (float*)d_out, N);
}